// Round 4
// baseline (283.386 us; speedup 1.0000x reference)
//
#include <hip/hip_runtime.h>

#define BATCH   16384
#define NUM_NEG 64
#define NSAMP   65          // 1 target + 64 negatives
#define EMBED   128
#define VOCAB   1000000
#define NPAIRS  (BATCH * NSAMP)      // 1,064,960
#define SCAN_ELEMS 1024
#define SCAN_NBLK  977               // ceil(VOCAB / 1024)

// ---------------- ws layout ----------------
// [0,          4,194,304)  hist / bin offsets (VOCAB u32, padded)
// [4,194,304,  4,259,840)  scan partials (977 u32, padded to 64KB)
// [4,259,840, 12,779,520)  pairs (NPAIRS x u64: hi=vocab idx, lo=out slot)
// [12,779,520,21,168,128)  densified context embeds (BATCH x 128 f32)
#define OFF_PART  4194304
#define OFF_PAIRS 4259840
#define OFF_CTX   12779520
#define WS_NEED   21168128

// ---------- sort pipeline ----------

__global__ __launch_bounds__(256)
void k_zero(unsigned int* __restrict__ hist)
{
    hist[blockIdx.x * 256 + threadIdx.x] = 0u;   // grid 4096 -> 4MB region
}

__global__ __launch_bounds__(256)
void k_hist(const int* __restrict__ target, const int* __restrict__ negatives,
            unsigned int* __restrict__ hist)
{
    const int t = blockIdx.x * 256 + threadIdx.x;    // grid 4160 -> exactly NPAIRS
    const int b = t / NSAMP, s = t - b * NSAMP;
    const int idx = (s == 0) ? target[b] : negatives[b * NUM_NEG + (s - 1)];
    atomicAdd(&hist[idx], 1u);
}

__global__ __launch_bounds__(256)
void k_scan_local(unsigned int* __restrict__ hist, unsigned int* __restrict__ partials)
{
    __shared__ unsigned int lds[256];
    const int base = blockIdx.x * SCAN_ELEMS + threadIdx.x * 4;
    unsigned int v[4], s = 0;
    #pragma unroll
    for (int j = 0; j < 4; ++j) {
        const unsigned int x = (base + j < VOCAB) ? hist[base + j] : 0u;
        v[j] = x; s += x;
    }
    lds[threadIdx.x] = s;
    __syncthreads();
    for (int off = 1; off < 256; off <<= 1) {
        const unsigned int t = (threadIdx.x >= off) ? lds[threadIdx.x - off] : 0u;
        __syncthreads();
        lds[threadIdx.x] += t;
        __syncthreads();
    }
    if (threadIdx.x == 255) partials[blockIdx.x] = lds[255];
    unsigned int run = lds[threadIdx.x] - s;         // exclusive prefix
    #pragma unroll
    for (int j = 0; j < 4; ++j) {
        const unsigned int x = v[j];
        if (base + j < VOCAB) hist[base + j] = run;
        run += x;
    }
}

__global__ __launch_bounds__(1024)
void k_scan_part(unsigned int* __restrict__ partials, int n)
{
    __shared__ unsigned int lds[1024];
    const int t = threadIdx.x;
    const unsigned int x = (t < n) ? partials[t] : 0u;
    lds[t] = x;
    __syncthreads();
    for (int off = 1; off < 1024; off <<= 1) {
        const unsigned int v = (t >= off) ? lds[t - off] : 0u;
        __syncthreads();
        lds[t] += v;
        __syncthreads();
    }
    if (t < n) partials[t] = lds[t] - x;             // exclusive
}

__global__ __launch_bounds__(256)
void k_addback(unsigned int* __restrict__ hist, const unsigned int* __restrict__ partials)
{
    const int base = blockIdx.x * SCAN_ELEMS + threadIdx.x * 4;
    const unsigned int add = partials[blockIdx.x];
    #pragma unroll
    for (int j = 0; j < 4; ++j)
        if (base + j < VOCAB) hist[base + j] += add;
}

__global__ __launch_bounds__(256)
void k_scatter(const int* __restrict__ target, const int* __restrict__ negatives,
               unsigned int* __restrict__ off, unsigned long long* __restrict__ pairs)
{
    const int t = blockIdx.x * 256 + threadIdx.x;    // grid 4160 -> exactly NPAIRS
    const int b = t / NSAMP, s = t - b * NSAMP;
    const int idx = (s == 0) ? target[b] : negatives[b * NUM_NEG + (s - 1)];
    const unsigned int pos = atomicAdd(&off[idx], 1u);
    pairs[pos] = ((unsigned long long)(unsigned int)idx << 32)
               | (unsigned int)(b * NSAMP + s);
}

__global__ __launch_bounds__(256)
void k_densify(const int* __restrict__ context, const float* __restrict__ emb_table,
               float* __restrict__ ctx)
{
    const int b = blockIdx.x * 2 + (threadIdx.x >> 7);   // grid 8192
    const int e = threadIdx.x & 127;
    const int c = context[b];
    ctx[(size_t)b * EMBED + e] = emb_table[(size_t)c * EMBED + e];
}

// Sorted dot: pairs are ascending in vocab idx -> near-streaming w_table reads.
// One 32-lane half processes 8 consecutive pairs; grid 16640 x 256 covers
// exactly NPAIRS (no tail).
__global__ __launch_bounds__(256)
void k_dot(const unsigned long long* __restrict__ pairs,
           const float* __restrict__ w_table, const float* __restrict__ b_table,
           const float* __restrict__ ctx, float* __restrict__ out)
{
    const int l32  = threadIdx.x & 31;
    const int base = (blockIdx.x * 8 + (threadIdx.x >> 5)) * 8;

    float4 wv[8], cv[8];
    float  bias[8];
    int    slot[8];
    #pragma unroll
    for (int i = 0; i < 8; ++i) {
        const unsigned long long pr = pairs[base + i];
        const int idx = (int)(pr >> 32);
        slot[i] = (int)(pr & 0xffffffffu);
        wv[i]   = *reinterpret_cast<const float4*>(
                      &w_table[(size_t)idx * EMBED + 4 * l32]);
        bias[i] = b_table[idx];
        const int b = slot[i] / NSAMP;
        cv[i]   = *reinterpret_cast<const float4*>(
                      &ctx[(size_t)b * EMBED + 4 * l32]);
    }
    #pragma unroll
    for (int i = 0; i < 8; ++i) {
        float p = wv[i].x * cv[i].x + wv[i].y * cv[i].y
                + wv[i].z * cv[i].z + wv[i].w * cv[i].w;
        #pragma unroll
        for (int off = 16; off; off >>= 1)
            p += __shfl_xor(p, off, 32);
        if (l32 == 0)
            out[slot[i]] = p + bias[i];
    }
}

__global__ __launch_bounds__(256)
void k_softmax(float* __restrict__ out)
{
    const int lane = threadIdx.x & 63;
    const int r    = blockIdx.x * 4 + (threadIdx.x >> 6);   // grid 4096
    float* row = out + (size_t)r * NSAMP;

    const float x  = row[lane];
    const float x2 = (lane == 0) ? row[64] : -INFINITY;

    float m = fmaxf(x, x2);
    #pragma unroll
    for (int off = 32; off; off >>= 1)
        m = fmaxf(m, __shfl_xor(m, off, 64));

    const float p  = __expf(x - m);
    const float p2 = (lane == 0) ? __expf(x2 - m) : 0.0f;

    float sum = p + p2;
    #pragma unroll
    for (int off = 32; off; off >>= 1)
        sum += __shfl_xor(sum, off, 64);

    const float inv = 1.0f / sum;
    row[lane] = p * inv;
    if (lane == 0) row[64] = p2 * inv;
}

// ---------- fallback: round-2 gather kernel (98.6 us) ----------
__global__ __launch_bounds__(256)
void skipgram_fallback(const int* __restrict__ target,
                       const int* __restrict__ context,
                       const int* __restrict__ negatives,
                       const float* __restrict__ emb_table,
                       const float* __restrict__ w_table,
                       const float* __restrict__ b_table,
                       float* __restrict__ out)
{
    const int b    = blockIdx.x;
    const int tid  = threadIdx.x;
    const int wave = tid >> 6;
    const int half = (tid >> 5) & 1;
    const int l32  = tid & 31;
    const int lane = tid & 63;

    __shared__ int   s_idx[NSAMP];
    __shared__ float s_logit[NSAMP];

    if (tid < NSAMP)
        s_idx[tid] = (tid == 0) ? target[b] : negatives[b * NUM_NEG + (tid - 1)];
    __syncthreads();

    const int c = context[b];
    const float4 e4 = *reinterpret_cast<const float4*>(
        &emb_table[(size_t)c * EMBED + 4 * l32]);

    float4 w4[8];
    float  bias[8];
    #pragma unroll
    for (int i = 0; i < 8; ++i) {
        const int s   = 8 * i + 2 * wave + half;
        const int idx = s_idx[s];
        w4[i]   = *reinterpret_cast<const float4*>(
                      &w_table[(size_t)idx * EMBED + 4 * l32]);
        bias[i] = b_table[idx];
    }
    #pragma unroll
    for (int i = 0; i < 8; ++i) {
        const int s = 8 * i + 2 * wave + half;
        float p = e4.x * w4[i].x + e4.y * w4[i].y
                + e4.z * w4[i].z + e4.w * w4[i].w;
        #pragma unroll
        for (int off = 16; off; off >>= 1)
            p += __shfl_xor(p, off, 32);
        if (l32 == 0)
            s_logit[s] = p + bias[i];
    }
    if (wave == 1 && half == 0) {
        const int idx = s_idx[64];
        const float4 v = *reinterpret_cast<const float4*>(
            &w_table[(size_t)idx * EMBED + 4 * l32]);
        const float bb = b_table[idx];
        float p = e4.x * v.x + e4.y * v.y + e4.z * v.z + e4.w * v.w;
        #pragma unroll
        for (int off = 16; off; off >>= 1)
            p += __shfl_xor(p, off, 32);
        if (l32 == 0)
            s_logit[64] = p + bb;
    }
    __syncthreads();

    if (wave == 0) {
        const float x  = s_logit[lane];
        const float x2 = (lane == 0) ? s_logit[64] : -INFINITY;
        float m = fmaxf(x, x2);
        #pragma unroll
        for (int off = 32; off; off >>= 1)
            m = fmaxf(m, __shfl_xor(m, off, 64));
        const float p  = __expf(x - m);
        const float p2 = (lane == 0) ? __expf(x2 - m) : 0.0f;
        float sum = p + p2;
        #pragma unroll
        for (int off = 32; off; off >>= 1)
            sum += __shfl_xor(sum, off, 64);
        const float inv = 1.0f / sum;
        out[(size_t)b * NSAMP + lane] = p * inv;
        if (lane == 0)
            out[(size_t)b * NSAMP + 64] = p2 * inv;
    }
}

extern "C" void kernel_launch(void* const* d_in, const int* in_sizes, int n_in,
                              void* d_out, int out_size, void* d_ws, size_t ws_size,
                              hipStream_t stream)
{
    const int*   target    = (const int*)  d_in[0];
    const int*   context   = (const int*)  d_in[1];
    const int*   negatives = (const int*)  d_in[2];
    const float* emb_table = (const float*)d_in[3];
    const float* w_table   = (const float*)d_in[4];
    const float* b_table   = (const float*)d_in[5];
    float*       out       = (float*)      d_out;

    if (ws_size < (size_t)WS_NEED) {
        skipgram_fallback<<<BATCH, 256, 0, stream>>>(
            target, context, negatives, emb_table, w_table, b_table, out);
        return;
    }

    char* ws = (char*)d_ws;
    unsigned int*       hist     = (unsigned int*)       ws;
    unsigned int*       partials = (unsigned int*)      (ws + OFF_PART);
    unsigned long long* pairs    = (unsigned long long*)(ws + OFF_PAIRS);
    float*              ctx      = (float*)             (ws + OFF_CTX);

    k_zero     <<<4096,      256,  0, stream>>>(hist);
    k_hist     <<<4160,      256,  0, stream>>>(target, negatives, hist);
    k_scan_local<<<SCAN_NBLK,256,  0, stream>>>(hist, partials);
    k_scan_part<<<1,         1024, 0, stream>>>(partials, SCAN_NBLK);
    k_addback  <<<SCAN_NBLK, 256,  0, stream>>>(hist, partials);
    k_scatter  <<<4160,      256,  0, stream>>>(target, negatives, hist, pairs);
    k_densify  <<<8192,      256,  0, stream>>>(context, emb_table, ctx);
    k_dot      <<<16640,     256,  0, stream>>>(pairs, w_table, b_table, ctx, out);
    k_softmax  <<<4096,      256,  0, stream>>>(out);
}

// Round 5
// 101.849 us; speedup vs baseline: 2.7824x; 2.7824x over previous
//
#include <hip/hip_runtime.h>

#define BATCH   16384
#define NUM_NEG 64
#define NSAMP   65          // 1 target + 64 negatives
#define EMBED   128

// One block (256 threads = 4 waves) per batch row.
// float4 row loads: 32 lanes cover one 512B w-row, so each wave fetches TWO
// samples per VMEM instruction. All 8 row loads + bias loads of a wave are
// batch-issued before any reduction to keep ~4KB/wave in flight.
//
// Round-4 note: this kernel is at the random-gather pattern ceiling —
// FETCH_SIZE equals the unique-row floor (~334 MB), doubling per-wave MLP
// was perf-neutral (r3), and a full counting-sort reordering pipeline (r4)
// lost 185 us to its own overhead. ~3.35 TB/s effective is the HW service
// rate for random 512B rows out of a 512 MB table.
__global__ __launch_bounds__(256)
void skipgram_kernel(const int* __restrict__ target,
                     const int* __restrict__ context,
                     const int* __restrict__ negatives,
                     const float* __restrict__ emb_table,
                     const float* __restrict__ w_table,
                     const float* __restrict__ b_table,
                     float* __restrict__ out)
{
    const int b    = blockIdx.x;
    const int tid  = threadIdx.x;
    const int wave = tid >> 6;          // 0..3
    const int half = (tid >> 5) & 1;    // 0: lanes 0-31, 1: lanes 32-63
    const int l32  = tid & 31;
    const int lane = tid & 63;

    __shared__ int   s_idx[NSAMP];
    __shared__ float s_logit[NSAMP];

    // Stage the 65 sample indices.
    if (tid < NSAMP)
        s_idx[tid] = (tid == 0) ? target[b] : negatives[b * NUM_NEG + (tid - 1)];
    __syncthreads();

    // Context-embedding fragment: 4 consecutive elements per lane-of-32.
    // Same address across all halves/waves -> L1 broadcast after first fetch.
    const int c = context[b];
    const float4 e4 = *reinterpret_cast<const float4*>(
        &emb_table[(size_t)c * EMBED + 4 * l32]);

    // Samples 0..63: wave w, half h, iteration i -> s = 8*i + 2*w + h.
    // Batch-issue all 8 row loads + 8 bias loads first (max loads in flight).
    float4 w4[8];
    float  bias[8];
    #pragma unroll
    for (int i = 0; i < 8; ++i) {
        const int s   = 8 * i + 2 * wave + half;
        const int idx = s_idx[s];
        w4[i]   = *reinterpret_cast<const float4*>(
                      &w_table[(size_t)idx * EMBED + 4 * l32]);
        bias[i] = b_table[idx];
    }

    // Reduce: dot(e4, w4) summed across the 32-lane half; lane 0 of the half
    // holds the logit.
    #pragma unroll
    for (int i = 0; i < 8; ++i) {
        const int s = 8 * i + 2 * wave + half;
        float p = e4.x * w4[i].x + e4.y * w4[i].y
                + e4.z * w4[i].z + e4.w * w4[i].w;
        #pragma unroll
        for (int off = 16; off; off >>= 1)
            p += __shfl_xor(p, off, 32);
        if (l32 == 0)
            s_logit[s] = p + bias[i];
    }

    // Sample 64: wave 1, lanes 0-31 (keeps wave 0 free for the softmax tail).
    if (wave == 1 && half == 0) {
        const int idx = s_idx[64];
        const float4 v = *reinterpret_cast<const float4*>(
            &w_table[(size_t)idx * EMBED + 4 * l32]);
        const float bb = b_table[idx];
        float p = e4.x * v.x + e4.y * v.y + e4.z * v.z + e4.w * v.w;
        #pragma unroll
        for (int off = 16; off; off >>= 1)
            p += __shfl_xor(p, off, 32);
        if (l32 == 0)
            s_logit[64] = p + bb;
    }
    __syncthreads();

    // Wave 0: softmax over 65 logits. Lane l owns logit l; lane 0 also owns 64.
    if (wave == 0) {
        const float x  = s_logit[lane];
        const float x2 = (lane == 0) ? s_logit[64] : -INFINITY;

        float m = fmaxf(x, x2);
        #pragma unroll
        for (int off = 32; off; off >>= 1)
            m = fmaxf(m, __shfl_xor(m, off, 64));

        const float p  = __expf(x - m);
        const float p2 = (lane == 0) ? __expf(x2 - m) : 0.0f;

        float sum = p + p2;
        #pragma unroll
        for (int off = 32; off; off >>= 1)
            sum += __shfl_xor(sum, off, 64);

        const float inv = 1.0f / sum;
        out[(size_t)b * NSAMP + lane] = p * inv;
        if (lane == 0)
            out[(size_t)b * NSAMP + 64] = p2 * inv;
    }
}

extern "C" void kernel_launch(void* const* d_in, const int* in_sizes, int n_in,
                              void* d_out, int out_size, void* d_ws, size_t ws_size,
                              hipStream_t stream)
{
    const int*   target    = (const int*)  d_in[0];
    const int*   context   = (const int*)  d_in[1];
    const int*   negatives = (const int*)  d_in[2];
    const float* emb_table = (const float*)d_in[3];
    const float* w_table   = (const float*)d_in[4];
    const float* b_table   = (const float*)d_in[5];
    float*       out       = (float*)      d_out;

    skipgram_kernel<<<BATCH, 256, 0, stream>>>(
        target, context, negatives, emb_table, w_table, b_table, out);
}